// Round 1
// 503.068 us; speedup vs baseline: 1.1706x; 1.1706x over previous
//
#include <hip/hip_runtime.h>
#include <hip/hip_bf16.h>
#include <stdint.h>

typedef float v4f __attribute__((ext_vector_type(4)));
typedef short v8s __attribute__((ext_vector_type(8)));

#define GEMM_M 8192
#define GEMM_N 4096
#define GEMM_K 4096
#define BM 256
#define BN 256
#define BK 64
#define NT (GEMM_K / BK)   // 64 K-tiles

// ---------------- prep ----------------

__device__ __forceinline__ uint16_t f2bf(float f) {
    union { float f; uint32_t u; } v; v.f = f;
    uint32_t r = v.u + 0x7FFFu + ((v.u >> 16) & 1u);   // round-to-nearest-even
    return (uint16_t)(r >> 16);
}

__device__ __forceinline__ float bf2f(uint16_t h) {
    union { uint32_t u; float f; } v; v.u = ((uint32_t)h) << 16;
    return v.f;
}

__device__ __forceinline__ void cvt8(const float* __restrict__ s, uint16_t* __restrict__ d) {
    float4 a = ((const float4*)s)[0];
    float4 b = ((const float4*)s)[1];
    union { v8s v; uint16_t u[8]; } o;
    o.u[0] = f2bf(a.x); o.u[1] = f2bf(a.y); o.u[2] = f2bf(a.z); o.u[3] = f2bf(a.w);
    o.u[4] = f2bf(b.x); o.u[5] = f2bf(b.y); o.u[6] = f2bf(b.z); o.u[7] = f2bf(b.w);
    *(v8s*)d = o.v;
}

__global__ void prep_cvt_kernel(const float* __restrict__ X, const float* __restrict__ W,
                                uint16_t* __restrict__ Xb, uint16_t* __restrict__ Wb,
                                size_t x8) {
    size_t i = (size_t)blockIdx.x * blockDim.x + threadIdx.x;
    if (i < x8) {
        cvt8(X + i * 8, Xb + i * 8);
    } else {
        size_t j = i - x8;
        cvt8(W + j * 8, Wb + j * 8);
    }
}

__global__ void scatter_bf16_kernel(uint16_t* __restrict__ Wb, const float* __restrict__ vals,
                                    const int* __restrict__ rows, const int* __restrict__ cols,
                                    int nnz) {
    int i = blockIdx.x * blockDim.x + threadIdx.x;
    if (i >= nnz) return;
    size_t idx = (size_t)rows[i] * GEMM_K + cols[i];
    uint32_t* addr = (uint32_t*)Wb + (idx >> 1);
    const bool hi = idx & 1;
    const float v = vals[i];   // * SCALING=1.0
    uint32_t cur = *addr, assumed;
    do {
        assumed = cur;
        uint16_t h = hi ? (uint16_t)(assumed >> 16) : (uint16_t)(assumed & 0xFFFFu);
        uint16_t nh = f2bf(bf2f(h) + v);
        uint32_t nw = hi ? ((assumed & 0x0000FFFFu) | ((uint32_t)nh << 16))
                         : ((assumed & 0xFFFF0000u) | (uint32_t)nh);
        if (nw == assumed) break;
        cur = atomicCAS(addr, assumed, nw);
    } while (cur != assumed);
}

// ---------------- GEMM: 256x256 tile, 8-wave, 8-phase counted-vmcnt schedule ----------------
// C[M,N] = A[M,K] bf16 * B[N,K]^T bf16 + bias[N], fp32 out.
//
// Structure (T1+T2+T3+T4+T5 per the technique catalog):
//  - LDS = 2 dbuf x 2 half x [128 rows x 64 k] x {A,B} = 128 KiB. Chunk-XOR swizzle
//    (stored chunk = logical_chunk ^ (row&7); pre-swizzled global source, swizzled read)
//    -- proven 0-bank-conflict in the previous kernel.
//  - Per K-tile (BK=64): 4 phases, each = {ds_read new frags; stage 1 half-tile
//    (2x global_load_lds dwordx4); s_barrier; lgkmcnt(0); setprio(1); 16 MFMA; setprio(0);
//    s_barrier}. Quadrant order (qm,qn) = (0,0),(1,0),(0,1),(1,1); frag regs reused so
//    reads/phase = 12,4,8,0 (24/tile minimum).
//  - Stage schedule: P0 stages B1(t+1); P1 A0(t+2); P2 A1(t+2); P3 B0(t+2). Each target
//    slot's last LDS read was >=1 barrier earlier. FIFO arithmetic: at each P3 the 8 oldest
//    outstanding loads are exactly tile t+1's 4 halves -> ONE s_waitcnt vmcnt(6) per tile,
//    never vmcnt(0) in the main loop (3 half-tiles stay in flight across the boundary).
//  - Prologue: tile0 (4 halves) + 3 halves of tile1, vmcnt(6), barrier.
//  - Waves: 8 = 4(m) x 2(n) within each 128x128 quadrant; wave computes 2m x 4n frags/phase.

__device__ __forceinline__ void gload_lds16(const void* g, void* lds) {
    __builtin_amdgcn_global_load_lds(
        (const __attribute__((address_space(1))) void*)(uintptr_t)g,
        (__attribute__((address_space(3))) void*)(uintptr_t)lds,
        16, 0, 0);
}

__global__ __launch_bounds__(512, 2) void gemm_bt_kernel(
    const uint16_t* __restrict__ A,   // [M,K] bf16 bits
    const uint16_t* __restrict__ B,   // [N,K] bf16 bits
    const float* __restrict__ bias,   // [N]
    float* __restrict__ C)            // [M,N] fp32
{
    __shared__ __attribute__((aligned(16))) uint16_t As[2][2][128 * BK];  // 64 KiB
    __shared__ __attribute__((aligned(16))) uint16_t Bs[2][2][128 * BK];  // 64 KiB

    const int tid  = threadIdx.x;
    const int lane = tid & 63;
    const int wid  = tid >> 6;     // 0..7
    const int wm2  = wid >> 1;     // 0..3: 32-row band within the 128-row quadrant half
    const int wn2  = wid & 1;      // 0..1: 64-col band
    const int lrow = lane & 15;
    const int quad = lane >> 4;
    const int xr   = lane & 7;     // == lrow & 7

    // T1: bijective XCD swizzle (512 % 8 == 0). Each XCD owns 4 consecutive m-panels.
    const int bid = blockIdx.x;               // 0..511
    const int swz = (bid & 7) * 64 + (bid >> 3);
    const int m0  = (swz >> 4) * BM;          // 32 m-tiles
    const int n0  = (swz & 15) * BN;          // 16 n-tiles

    // staging geometry: transfer (wid, i, lane) covers half rows wid*16 + i*8 + (lane>>3);
    // lane fetches pre-swizzled global k-chunk ((lane&7)^(lane>>3)); LDS dest is linear.
    const int srow = wid * 16 + (lane >> 3);
    const int skc  = ((lane & 7) ^ (lane >> 3)) * 8;
    const uint16_t* gA = A + (size_t)(m0 + srow) * GEMM_K + skc;
    const uint16_t* gB = B + (size_t)(n0 + srow) * GEMM_K + skc;
    const int ldso = wid * 1024 + lane * 8;   // elem offset within one 8192-elem half

#define STAGE(gbase, hrow, s, ldshalf)  do {                                   \
        const uint16_t* _g = (gbase) + (size_t)(hrow) * GEMM_K + (s) * BK;     \
        uint16_t* _l = (ldshalf) + ldso;                                       \
        gload_lds16(_g, _l);                                                   \
        gload_lds16(_g + (size_t)8 * GEMM_K, _l + 512);                        \
    } while (0)

    v4f acc00[2][4], acc10[2][4], acc01[2][4], acc11[2][4];
#pragma unroll
    for (int mi = 0; mi < 2; ++mi)
#pragma unroll
        for (int nj = 0; nj < 4; ++nj) {
            acc00[mi][nj] = (v4f){0.f, 0.f, 0.f, 0.f};
            acc10[mi][nj] = (v4f){0.f, 0.f, 0.f, 0.f};
            acc01[mi][nj] = (v4f){0.f, 0.f, 0.f, 0.f};
            acc11[mi][nj] = (v4f){0.f, 0.f, 0.f, 0.f};
        }

    v8s a0F[2][2], a1F[2][2], bF[4][2];   // all statically indexed (rule #20)

    // fragment read: half-local row rh holds logical chunk c at elem rh*64 + ((c^(rh&7))*8)
#define LDA(dst, hp) do {                                                      \
        _Pragma("unroll")                                                      \
        for (int mi = 0; mi < 2; ++mi)                                         \
        _Pragma("unroll")                                                      \
        for (int ks = 0; ks < 2; ++ks) {                                       \
            const int rh = wm2 * 32 + mi * 16 + lrow;                          \
            const int c  = ks * 4 + quad;                                      \
            dst[mi][ks] = *(const v8s*)((hp) + rh * BK + ((c ^ xr) << 3));     \
        } } while (0)

#define LDB(hp) do {                                                           \
        _Pragma("unroll")                                                      \
        for (int nj = 0; nj < 4; ++nj)                                         \
        _Pragma("unroll")                                                      \
        for (int ks = 0; ks < 2; ++ks) {                                       \
            const int rh = wn2 * 64 + nj * 16 + lrow;                          \
            const int c  = ks * 4 + quad;                                      \
            bF[nj][ks] = *(const v8s*)((hp) + rh * BK + ((c ^ xr) << 3));      \
        } } while (0)

#define MM(accq, aT) do {                                                      \
        _Pragma("unroll")                                                      \
        for (int ks = 0; ks < 2; ++ks)                                         \
        _Pragma("unroll")                                                      \
        for (int mi = 0; mi < 2; ++mi)                                         \
        _Pragma("unroll")                                                      \
        for (int nj = 0; nj < 4; ++nj)                                         \
            accq[mi][nj] = __builtin_amdgcn_mfma_f32_16x16x32_bf16(            \
                aT[mi][ks], bF[nj][ks], accq[mi][nj], 0, 0, 0);                \
    } while (0)

#define BAR()   __builtin_amdgcn_s_barrier()
#define LGKM0() asm volatile("s_waitcnt lgkmcnt(0)" ::: "memory")
#define VM6()   asm volatile("s_waitcnt vmcnt(6)" ::: "memory")
#define SCHED() __builtin_amdgcn_sched_barrier(0)

    // ---- prologue: tile0 fully + 3 halves of tile1; vmcnt(6) leaves those 3 in flight ----
    STAGE(gA, 0,   0, &As[0][0][0]);
    STAGE(gA, 128, 0, &As[0][1][0]);
    STAGE(gB, 0,   0, &Bs[0][0][0]);
    STAGE(gB, 128, 0, &Bs[0][1][0]);
    STAGE(gA, 0,   1, &As[1][0][0]);
    STAGE(gA, 128, 1, &As[1][1][0]);
    STAGE(gB, 0,   1, &Bs[1][0][0]);
    SCHED(); VM6();
    BAR();

#define TILE(t, b) do {                                                        \
        const int s1 = ((t) + 1) & (NT - 1);                                   \
        const int s2 = ((t) + 2) & (NT - 1);                                   \
        /* P0: quadrant (0,0) */                                               \
        LDA(a0F, &As[b][0][0]);                                                \
        LDB(&Bs[b][0][0]);                                                     \
        STAGE(gB, 128, s1, &Bs[(b) ^ 1][1][0]);                                \
        SCHED(); BAR(); LGKM0(); SCHED();                                      \
        __builtin_amdgcn_s_setprio(1); MM(acc00, a0F); __builtin_amdgcn_s_setprio(0); \
        SCHED(); BAR();                                                        \
        /* P1: quadrant (1,0) */                                               \
        LDA(a1F, &As[b][1][0]);                                                \
        STAGE(gA, 0, s2, &As[b][0][0]);                                        \
        SCHED(); BAR(); LGKM0(); SCHED();                                      \
        __builtin_amdgcn_s_setprio(1); MM(acc10, a1F); __builtin_amdgcn_s_setprio(0); \
        SCHED(); BAR();                                                        \
        /* P2: quadrant (0,1) */                                               \
        LDB(&Bs[b][1][0]);                                                     \
        STAGE(gA, 128, s2, &As[b][1][0]);                                      \
        SCHED(); BAR(); LGKM0(); SCHED();                                      \
        __builtin_amdgcn_s_setprio(1); MM(acc01, a0F); __builtin_amdgcn_s_setprio(0); \
        SCHED(); BAR();                                                        \
        /* P3: quadrant (1,1); the one counted vmcnt of this K-tile */         \
        STAGE(gB, 0, s2, &Bs[b][0][0]);                                        \
        SCHED(); VM6();                                                        \
        BAR();                                                                 \
        __builtin_amdgcn_s_setprio(1); MM(acc11, a1F); __builtin_amdgcn_s_setprio(0); \
        SCHED(); BAR();                                                        \
    } while (0)

    for (int t = 0; t < NT; t += 2) {
        TILE(t, 0);
        TILE(t + 1, 1);
    }

    // epilogue: C/D layout col = lane&15, row = quad*4 + reg  [m89/m91 verified]
#define WR(accq, QM, QN) do {                                                  \
        _Pragma("unroll")                                                      \
        for (int nj = 0; nj < 4; ++nj) {                                       \
            const int col = n0 + (QN) * 128 + wn2 * 64 + nj * 16 + lrow;       \
            const float bj = bias[col];                                        \
            _Pragma("unroll")                                                  \
            for (int mi = 0; mi < 2; ++mi) {                                   \
                const int row = m0 + (QM) * 128 + wm2 * 32 + mi * 16 + quad * 4; \
                float* cp = C + (size_t)row * GEMM_N + col;                    \
                _Pragma("unroll")                                              \
                for (int r = 0; r < 4; ++r)                                    \
                    cp[(size_t)r * GEMM_N] = accq[mi][nj][r] + bj;             \
            }                                                                  \
        } } while (0)

    WR(acc00, 0, 0);
    WR(acc10, 1, 0);
    WR(acc01, 0, 1);
    WR(acc11, 1, 1);

#undef STAGE
#undef LDA
#undef LDB
#undef MM
#undef BAR
#undef LGKM0
#undef VM6
#undef SCHED
#undef TILE
#undef WR
}

// ---------------- launch ----------------

extern "C" void kernel_launch(void* const* d_in, const int* in_sizes, int n_in,
                              void* d_out, int out_size, void* d_ws, size_t ws_size,
                              hipStream_t stream) {
    const float* x      = (const float*)d_in[0];   // [4,2048,4096] = [8192,4096]
    const float* weight = (const float*)d_in[1];   // [4096,4096]
    const float* bias   = (const float*)d_in[2];   // [4096]
    const float* sw     = (const float*)d_in[3];   // [nnz]
    const int*   sidx   = (const int*)d_in[4];     // [2,nnz]
    const int nnz = in_sizes[3];

    const size_t welems = (size_t)GEMM_N * GEMM_K;        // 16,777,216
    const size_t xelems = (size_t)GEMM_M * GEMM_K;        // 33,554,432

    uint16_t* Wb = (uint16_t*)d_ws;
    uint16_t* Xb = (uint16_t*)((char*)d_ws + welems * sizeof(uint16_t));

    const size_t x8 = xelems / 8;
    const size_t w8 = welems / 8;
    const int prep_blocks = (int)((x8 + w8) / 256);

    prep_cvt_kernel<<<dim3(prep_blocks), 256, 0, stream>>>(x, weight, Xb, Wb, x8);
    scatter_bf16_kernel<<<dim3((nnz + 255) / 256), 256, 0, stream>>>(
        Wb, sw, sidx, sidx + nnz, nnz);
    gemm_bt_kernel<<<dim3((GEMM_M / BM) * (GEMM_N / BN)), 512, 0, stream>>>(
        Xb, Wb, bias, (float*)d_out);
}